// Round 12
// baseline (733.075 us; speedup 1.0000x reference)
//
#include <hip/hip_runtime.h>
#include <math.h>

// All inputs and the output are FLOAT32 (reference dtype).

#define HH 512
#define WWI 512
#define HWP (HH*WWI)

// ---------------- layer 0: 1x1 conv on upsampled 2x2 + leakyrelu + coordconv ----------------
__global__ void k_layer0(const float* __restrict__ xin, const float* __restrict__ w,
                         const float* __restrict__ bias, float* __restrict__ out)
{
  for (int idx = threadIdx.x; idx < 3*66*4; idx += blockDim.x) {
    int pos = idx & 3;
    int c = (idx >> 2) % 66;
    int b = idx / (66*4);
    float v;
    if (c < 64) {
      float a = bias[c];
      #pragma unroll
      for (int ci = 0; ci < 3; ci++) a += w[c*3+ci] * xin[b*3+ci];
      v = (a >= 0.f) ? a : 0.01f*a;
    } else {
      int xx = pos & 1, yy = pos >> 1;
      v = (c == 64) ? 2.f*(float)xx : 2.f*(float)yy;
    }
    out[idx] = v;
  }
}

__device__ __forceinline__ int refl_up(int t, int n) {
  t = (t < 0) ? -t : t;
  t = (t >= n) ? (2*(n-1) - t) : t;
  return t >> 1;
}

// ---------------- LDS conv for small layers L1-L5 (R7-proven) ----------------
template<int G>
__global__ void k_conv_lds(const float* __restrict__ in, float* __restrict__ out,
                           const float* __restrict__ w, const float* __restrict__ bias,
                           int B, int Cin, int CO, int COB, int Hin, int TR, int SPAN)
{
  extern __shared__ float lds[];
  const int Hout = Hin * 2;
  const int rowTiles = Hout / TR;
  const int coTiles = CO / COB;
  int bid = blockIdx.x;
  int tile = bid % rowTiles;
  int cot  = (bid / rowTiles) % coTiles;
  int b    = bid / (rowTiles * coTiles);
  int tr0  = tile * TR;
  int co_base = cot * COB;

  int r0 = tr0/2 - 1;
  if (r0 < 0) r0 = 0;
  if (r0 > Hin - SPAN) r0 = Hin - SPAN;

  float* wlds = lds;
  float* blds = wlds + COB*Cin*9;
  float* ilds = blds + COB;

  int nt = blockDim.x, tid = threadIdx.x;

  const float* wsrc = w + (size_t)co_base*Cin*9;
  for (int i = tid; i < COB*Cin*9; i += nt) wlds[i] = wsrc[i];
  for (int i = tid; i < COB; i += nt) blds[i] = bias[co_base + i];
  int icount = Cin*SPAN*Hin;
  for (int i = tid; i < icount; i += nt) {
    int col = i % Hin;
    int r = (i / Hin) % SPAN;
    int ci = i / (Hin*SPAN);
    ilds[i] = in[(((size_t)b*Cin + ci)*Hin + (r0 + r))*Hin + col];
  }
  __syncthreads();

  int npix = TR * Hout;
  int ngr = COB / G;
  int items = ngr * npix;
  for (int it = tid; it < items; it += nt) {
    int pix = it % npix;
    int cg = it / npix;
    int x = pix % Hout;
    int y = tr0 + pix / Hout;

    int ry[3], rx[3];
    #pragma unroll
    for (int d = 0; d < 3; d++) {
      int s = refl_up(y - 1 + d, Hout) - r0;
      s = (s < 0) ? 0 : s;
      s = (s > SPAN-1) ? SPAN-1 : s;
      ry[d] = s;
      rx[d] = refl_up(x - 1 + d, Hout);
    }

    float acc[G];
    #pragma unroll
    for (int j = 0; j < G; j++) acc[j] = blds[cg*G + j];

    for (int ci = 0; ci < Cin; ci++) {
      const float* ib = ilds + (size_t)ci*SPAN*Hin;
      float p[9];
      #pragma unroll
      for (int dy = 0; dy < 3; dy++)
        #pragma unroll
        for (int dx = 0; dx < 3; dx++)
          p[dy*3+dx] = ib[ry[dy]*Hin + rx[dx]];
      const float* wc = wlds + ((size_t)(cg*G)*Cin + ci)*9;
      #pragma unroll
      for (int j = 0; j < G; j++) {
        #pragma unroll
        for (int k = 0; k < 9; k++) acc[j] += wc[(size_t)j*Cin*9 + k] * p[k];
      }
    }

    #pragma unroll
    for (int j = 0; j < G; j++) {
      float v = acc[j];
      v = (v >= 0.f) ? v : 0.01f*v;
      out[(((size_t)b*CO + co_base + cg*G + j)*Hout + y)*Hout + x] = v;
    }
  }
}

// ---------------- pipelined upconv: R7 mapping + compile-time Cin + tap prefetch ----------------
// thread = output pixel, all CO channels. Weights via wave-uniform s_load (R7-proven).
// ci-loop fully unrolled; taps for ci+1 issued before FMAs of ci -> latency overlapped.
template<int CO_, int CIN>
__global__ void k_upconv_t(const float* __restrict__ in, float* __restrict__ out,
                           const float* __restrict__ w, const float* __restrict__ bias,
                           int B, int Hin)
{
  int Hout = Hin * 2;
  int total = B * Hout * Hout;
  int idx = blockIdx.x*blockDim.x + threadIdx.x;
  if (idx >= total) return;
  int x = idx % Hout;
  int y = (idx / Hout) % Hout;
  int b = idx / (Hout * Hout);

  int ry[3], rx[3];
  #pragma unroll
  for (int d = 0; d < 3; d++) {
    ry[d] = refl_up(y - 1 + d, Hout);
    rx[d] = refl_up(x - 1 + d, Hout);
  }
  int off[9];
  #pragma unroll
  for (int dy = 0; dy < 3; dy++)
    #pragma unroll
    for (int dx = 0; dx < 3; dx++)
      off[dy*3+dx] = ry[dy]*Hin + rx[dx];

  const float* base = in + (size_t)b*CIN*Hin*Hin;
  const int plane = Hin*Hin;

  float acc[CO_];
  #pragma unroll
  for (int co = 0; co < CO_; co++) acc[co] = bias[co];

  float p[9];
  #pragma unroll
  for (int k = 0; k < 9; k++) p[k] = base[off[k]];

  #pragma unroll
  for (int ci = 0; ci < CIN; ci++) {
    float pn[9];
    if (ci + 1 < CIN) {
      const float* nb = base + (size_t)(ci+1)*plane;
      #pragma unroll
      for (int k = 0; k < 9; k++) pn[k] = nb[off[k]];
    }
    const float* wc = w + ci*9;
    #pragma unroll
    for (int co = 0; co < CO_; co++) {
      const float* wcc = wc + co*CIN*9;
      #pragma unroll
      for (int k = 0; k < 9; k++) acc[co] += wcc[k] * p[k];
    }
    if (ci + 1 < CIN) {
      #pragma unroll
      for (int k = 0; k < 9; k++) p[k] = pn[k];
    }
  }

  int pix = y*Hout + x;
  #pragma unroll
  for (int co = 0; co < CO_; co++) {
    float v = acc[co];
    v = (v >= 0.f) ? v : 0.01f*v;
    out[((size_t)(b*CO_) + co)*(Hout*Hout) + pix] = v;
  }
}

// ---------------- pipelined final conv: 16->6 + tanh, INTERLEAVED output [b][pix][6] -----------
__global__ void k_final_t(const float* __restrict__ in, float* __restrict__ out,
                          const float* __restrict__ w, const float* __restrict__ bias)
{
  int idx = blockIdx.x*blockDim.x + threadIdx.x;
  int total = 3 * HWP;
  if (idx >= total) return;
  int x = idx & (WWI-1);
  int y = (idx >> 9) & (HH-1);
  int b = idx / HWP;

  int ry[3], rx[3];
  #pragma unroll
  for (int d = 0; d < 3; d++) {
    int t = y - 1 + d;
    t = (t < 0) ? -t : t;
    ry[d] = (t >= HH) ? (2*(HH-1) - t) : t;
    t = x - 1 + d;
    t = (t < 0) ? -t : t;
    rx[d] = (t >= WWI) ? (2*(WWI-1) - t) : t;
  }
  int off[9];
  #pragma unroll
  for (int dy = 0; dy < 3; dy++)
    #pragma unroll
    for (int dx = 0; dx < 3; dx++)
      off[dy*3+dx] = ry[dy]*WWI + rx[dx];

  const float* base = in + (size_t)b*16*HWP;

  float acc[6];
  #pragma unroll
  for (int co = 0; co < 6; co++) acc[co] = bias[co];

  float p[9];
  #pragma unroll
  for (int k = 0; k < 9; k++) p[k] = base[off[k]];

  #pragma unroll
  for (int ci = 0; ci < 16; ci++) {
    float pn[9];
    if (ci + 1 < 16) {
      const float* nb = base + (size_t)(ci+1)*HWP;
      #pragma unroll
      for (int k = 0; k < 9; k++) pn[k] = nb[off[k]];
    }
    const float* wc = w + ci*9;
    #pragma unroll
    for (int co = 0; co < 6; co++) {
      const float* wcc = wc + co*16*9;
      #pragma unroll
      for (int k = 0; k < 9; k++) acc[co] += wcc[k] * p[k];
    }
    if (ci + 1 < 16) {
      #pragma unroll
      for (int k = 0; k < 9; k++) p[k] = pn[k];
    }
  }

  int pix = y*WWI + x;
  float* o = out + ((size_t)b*HWP + pix)*6;
  #pragma unroll
  for (int co = 0; co < 6; co++)
    o[co] = tanhf(acc[co]);
}

// ---------------- blending (flows interleaved [b][pix][6], R8-proven numerics) ----------------
__global__ void k_blend(const float* __restrict__ xin, const float* __restrict__ neighbors,
                        const int* __restrict__ aidx, const float* __restrict__ albedos,
                        const float* __restrict__ flows, float* __restrict__ out)
{
  int idx = blockIdx.x*blockDim.x + threadIdx.x;
  if (idx >= HWP) return;
  int xo = idx & (WWI-1);
  int yo = idx >> 9;

  float xv[9];
  #pragma unroll
  for (int i = 0; i < 9; i++) xv[i] = xin[i];

  float f0[6];
  const float* f0p = flows + (size_t)idx*6;
  #pragma unroll
  for (int c = 0; c < 6; c++) f0[c] = f0p[c];

  const float* alb = albedos + (size_t)aidx[0]*3*HWP;
  float albp[3];
  #pragma unroll
  for (int ch = 0; ch < 3; ch++) albp[ch] = alb[(size_t)ch*HWP + idx];

  float num0 = 0.f, num1 = 0.f, num2 = 0.f;
  float wsum = 0.f;

  #pragma unroll
  for (int n = 0; n < 2; n++) {
    float dl = xv[0] - xv[(n+1)*3 + 0];
    float dv = xv[1] - xv[(n+1)*3 + 1];
    float dt = xv[2] - xv[(n+1)*3 + 2];
    bool fl = fabsf(dl) > 0.f;

    float ofx = dl*f0[0] + dv*f0[2] + dt*f0[4];
    float ofy = dl*f0[1] + dv*f0[3] + dt*f0[5];

    float gx = ((-1.f + (2.f/511.f)*(float)xo) + ofx + 1.f)*256.f - 0.5f;
    float gy = ((-1.f + (2.f/511.f)*(float)yo) + ofy + 1.f)*256.f - 0.5f;
    gx = fminf(fmaxf(gx, 0.f), 511.f);
    gy = fminf(fmaxf(gy, 0.f), 511.f);

    float x0f = floorf(gx), y0f = floorf(gy);
    float wx = gx - x0f, wy = gy - y0f;
    int x0i = (int)x0f, y0i = (int)y0f;
    int x1i = min(x0i + 1, WWI-1), y1i = min(y0i + 1, HH-1);

    float cw[4] = {(1.f-wx)*(1.f-wy), wx*(1.f-wy), (1.f-wx)*wy, wx*wy};
    int   cp[4] = {y0i*WWI + x0i, y0i*WWI + x1i, y1i*WWI + x0i, y1i*WWI + x1i};

    const float* nb = neighbors + (size_t)n*3*HWP;
    const float* Fn = flows + (size_t)(n+1)*HWP*6;

    float s0=0.f,s1=0.f,s2=0.f;
    float l0=0.f,l1=0.f,v0=0.f,v1=0.f,t0=0.f,t1=0.f;
    #pragma unroll
    for (int c = 0; c < 4; c++) {
      int p = cp[c];
      float ww = cw[c];
      float n0 = nb[p];
      float n1 = nb[HWP + p];
      float n2 = nb[2*HWP + p];
      if (fl) {
        n0 /= alb[p];
        n1 /= alb[HWP + p];
        n2 /= alb[2*HWP + p];
      }
      s0 += ww*n0; s1 += ww*n1; s2 += ww*n2;
      const float* fp = Fn + (size_t)p*6;
      l0 += ww*fp[0]; l1 += ww*fp[1];
      v0 += ww*fp[2]; v1 += ww*fp[3];
      t0 += ww*fp[4]; t1 += ww*fp[5];
    }

    float wi0 = fl ? s0*albp[0] : s0;
    float wi1 = fl ? s1*albp[1] : s1;
    float wi2 = fl ? s2*albp[2] : s2;

    float obx = dl*l0 + dv*v0 + dt*t0;
    float oby = dl*l1 + dv*v1 + dt*t1;
    float dist = fabsf(ofx - obx) + fabsf(ofy - oby);
    float wgt = expf(-51.2f * dist);

    wsum += wgt;
    num0 += wgt*wi0; num1 += wgt*wi1; num2 += wgt*wi2;
  }

  float inv = 1.f / (wsum + 1e-5f);
  out[idx]         = num0*inv;
  out[HWP + idx]   = num1*inv;
  out[2*HWP + idx] = num2*inv;
}

// ---------------- launch ----------------
extern "C" void kernel_launch(void* const* d_in, const int* in_sizes, int n_in,
                              void* d_out, int out_size, void* d_ws, size_t ws_size,
                              hipStream_t stream) {
  const float* x         = (const float*)d_in[0];
  const float* neighbors = (const float*)d_in[1];
  const int*   aidx      = (const int*)d_in[2];
  const float* wts[10];
  const float* bis[10];
  for (int i = 0; i < 9; i++) { wts[i] = (const float*)d_in[3+2*i]; bis[i] = (const float*)d_in[4+2*i]; }
  wts[9] = (const float*)d_in[21];   // wf
  bis[9] = (const float*)d_in[22];   // bf
  const float* albedos = (const float*)d_in[23];

  float* wk   = (float*)d_ws;
  float* bufS = wk;                   // 792 floats
  float* bufA = wk + 800;             // 4,718,592 floats (L7 out; later flows [b][pix][6])
  float* bufB = bufA + 4718592;       // 12,582,912 floats (L8 out)
  size_t need = (size_t)(800 + 4718592 + 12582912) * 4;
  if (ws_size < need) return;

  k_layer0<<<1, 256, 0, stream>>>(x, wts[0], bis[0], bufS);

  auto spanOf = [](int Hin, int TR) { int s = TR/2 + 2; return (s > Hin) ? Hin : s; };
  auto ldsB = [&](int COB, int Cin, int Hin, int TR) {
    return (size_t)(COB*Cin*9 + COB + Cin*spanOf(Hin,TR)*Hin) * 4;
  };

  // L1-L5: LDS conv (R7-proven configs)
  k_conv_lds<1><<<12, 256, ldsB(16,66,2,4), stream>>>(bufS, bufA, wts[1], bis[1],
                                                      3, 66, 64, 16, 2, 4, spanOf(2,4));
  k_conv_lds<1><<<24, 256, ldsB(8,64,4,8), stream>>>(bufA, bufB, wts[2], bis[2],
                                                     3, 64, 64, 8, 4, 8, spanOf(4,8));
  k_conv_lds<2><<<24, 256, ldsB(4,64,8,16), stream>>>(bufB, bufA, wts[3], bis[3],
                                                      3, 64, 32, 4, 8, 16, spanOf(8,16));
  k_conv_lds<2><<<48, 256, ldsB(8,32,16,8), stream>>>(bufA, bufB, wts[4], bis[4],
                                                      3, 32, 32, 8, 16, 8, spanOf(16,8));
  k_conv_lds<4><<<96, 256, ldsB(8,32,32,8), stream>>>(bufB, bufA, wts[5], bis[5],
                                                      3, 32, 32, 8, 32, 8, spanOf(32,8));

  auto blocks = [](int total){ return (total + 255) / 256; };
  // L6-L8: pipelined plain-global kernels (R7 mapping + prefetch)
  k_upconv_t<16,32><<<blocks(3*128*128), 256, 0, stream>>>(bufA, bufB, wts[6], bis[6], 3, 64);
  k_upconv_t<16,16><<<blocks(3*256*256), 256, 0, stream>>>(bufB, bufA, wts[7], bis[7], 3, 128);
  k_upconv_t<16,16><<<blocks(3*512*512), 256, 0, stream>>>(bufA, bufB, wts[8], bis[8], 3, 256);

  // final: pipelined, writes flows interleaved into bufA (exactly 4,718,592 floats)
  k_final_t<<<blocks(3*HWP), 256, 0, stream>>>(bufB, bufA, wts[9], bis[9]);

  k_blend<<<blocks(HWP), 256, 0, stream>>>(x, neighbors, aidx, albedos, bufA, (float*)d_out);
}